// Round 1
// baseline (245.070 us; speedup 1.0000x reference)
//
#include <hip/hip_runtime.h>

#define L 256
#define BATCH 512
#define CIN 32
#define HIDN 128
#define OUTN 512

typedef _Float16 f16x8 __attribute__((ext_vector_type(8)));
typedef float f32x4 __attribute__((ext_vector_type(4)));

#define MFMA16(a, b, c) __builtin_amdgcn_mfma_f32_16x16x32_f16(a, b, c, 0, 0, 0)

static __device__ __forceinline__ unsigned short f16b(_Float16 h) {
    unsigned short u; __builtin_memcpy(&u, &h, 2); return u;
}

// ws layout (bytes):
//   Wh   @ 0        (32768)  fp16 hi of W_hh [j][k]
//   Wl   @ 32768    (32768)  fp16 lo residual
//   Wch  @ 65536    (8192)   fp16 hi of Wc = W_ih@W_in [j][c]
//   Wcl  @ 73728    (8192)
//   bpre @ 81920    (512)    fp32 b_ih + b_hh + W_ih@b_in
//   hs   @ 98304    (33554432) fp16 hs[t*65536 + b*128 + j]
//   xT   @ 33652736 (8421376)  fp16 xT[t][b][c], t slots = 257 (one pad slot so the
//                              in-loop prefetch for t+1==256 never branches)

// Block 0: weight prep (unchanged). Blocks 1..32: transpose x (B,C,L) f32 ->
// xT[t][b][c] f16 so rnn_kernel can load its x B-fragment as ONE coalesced
// dwordx4 instead of staging through a bank-conflicted LDS buffer.
__global__ __launch_bounds__(256) void prep_kernel(
    const float* __restrict__ x,
    const float* __restrict__ W_in, const float* __restrict__ b_in,
    const float* __restrict__ W_ih, const float* __restrict__ b_ih,
    const float* __restrict__ b_hh, const float* __restrict__ Whh,
    unsigned short* __restrict__ Wh, unsigned short* __restrict__ Wl,
    unsigned short* __restrict__ Wch, unsigned short* __restrict__ Wcl,
    float* __restrict__ bpre, unsigned short* __restrict__ xT)
{
    const int tid = threadIdx.x;

    if (blockIdx.x != 0) {
        // ---- transpose: 16 batch rows per block, 8 chunks of 32 t ----
        const int bb = blockIdx.x - 1;
        __shared__ float tile[32][16][33];   // [t_local][n][c] f32, c padded; c
                                             // XOR-swizzled by (t>>2)&3 to kill
                                             // write-side bank conflicts
        const int wv = tid >> 6, l = tid & 63;
        const int wn = l >> 2, wc0 = (l & 3) * 8;
        for (int tc = 0; tc < 8; ++tc) {
#pragma unroll
            for (int r = 0; r < 16; ++r) {
                int i = tid + r * 256;            // 16n x 32c x 8tq float4s
                int nn = i >> 8, cc = (i >> 3) & 31, tq = i & 7;
                float4 v = *(const float4*)(
                    x + ((size_t)(bb * 16 + nn) * CIN + cc) * L + tc * 32 + tq * 4);
                int cs = cc ^ ((tq & 3) << 3);    // swizzle: bank spread over tq
                tile[tq * 4 + 0][nn][cs] = v.x;
                tile[tq * 4 + 1][nn][cs] = v.y;
                tile[tq * 4 + 2][nn][cs] = v.z;
                tile[tq * 4 + 3][nn][cs] = v.w;
            }
            __syncthreads();
#pragma unroll
            for (int it = 0; it < 8; ++it) {
                int tl = wv + it * 4;
                int swz = ((tl >> 2) & 3) << 3;
                const float* src = &tile[tl][wn][wc0 ^ swz];
                unsigned short o[8];
#pragma unroll
                for (int k = 0; k < 8; ++k) o[k] = f16b((_Float16)src[k]);
                *(uint4*)(xT + ((size_t)(tc * 32 + tl) * BATCH + bb * 16 + wn) * CIN + wc0)
                    = *(uint4*)o;
            }
            __syncthreads();
        }
        return;
    }

    // ---- block 0: weights ----
    __shared__ float win[64 * CIN];
    for (int i = tid; i < 64 * CIN; i += 256) win[i] = W_in[i];
    __syncthreads();
    if (tid < 128) {
        const int j = tid;
        float acc[CIN];
#pragma unroll
        for (int c = 0; c < CIN; ++c) acc[c] = 0.f;
        float bs = b_ih[j] + b_hh[j];
        for (int m = 0; m < 64; ++m) {
            float w = W_ih[j * 64 + m];
            bs += w * b_in[m];
#pragma unroll
            for (int c = 0; c < CIN; ++c) acc[c] += w * win[m * CIN + c];
        }
        bpre[j] = bs;
#pragma unroll
        for (int c = 0; c < CIN; ++c) {
            _Float16 h = (_Float16)acc[c];
            _Float16 lo = (_Float16)(acc[c] - (float)h);
            Wch[j * CIN + c] = f16b(h);
            Wcl[j * CIN + c] = f16b(lo);
        }
    } else {
        const int j = tid - 128;
        for (int k = 0; k < HIDN; k += 4) {
            float4 v = *(const float4*)(Whh + j * HIDN + k);
            float vv[4] = {v.x, v.y, v.z, v.w};
#pragma unroll
            for (int u = 0; u < 4; ++u) {
                _Float16 h = (_Float16)vv[u];
                _Float16 lo = (_Float16)(vv[u] - (float)h);
                Wh[j * HIDN + k + u] = f16b(h);
                Wl[j * HIDN + k + u] = f16b(lo);
            }
        }
    }
}

// MFMA RNN, fp16 2-term split. 32 blocks (16 batch rows) x 512 thr (8 waves).
// R10: xc LDS staging removed (was 240 measured conflict-cycles/block-step plus
// ~8-way-conflicted xB reads sitting on the barrier critical path). x B-frags
// now come from pre-transposed xT via one coalesced dwordx4 per wave per step,
// register-prefetched one step ahead (stays in flight across the barrier —
// only lgkmcnt is drained there). MFMA chains split 5-deep -> 3+2 with the
// x-MFMA first (its operand arrived last step, so it issues before any
// ds_read lands). LDS is now just the 8 KB h ping-pong.
__global__ __launch_bounds__(512, 1) void rnn_kernel(
    const float* __restrict__ h0,
    const unsigned short* __restrict__ Wh, const unsigned short* __restrict__ Wl,
    const unsigned short* __restrict__ Wch, const unsigned short* __restrict__ Wcl,
    const float* __restrict__ bpre, const unsigned short* __restrict__ xT,
    unsigned short* __restrict__ hs)
{
    const int tid = threadIdx.x;
    const int bb = blockIdx.x;
    const int lane = tid & 63;
    const int w = tid >> 6;       // wave 0..7
    const int n = lane & 15;      // batch col / B col
    const int q = lane >> 4;      // quad

    __shared__ unsigned short hbuf[2][16][HIDN];     // 8 KB, granule swizzle ^(n&7)

    // A-frags: rows = j = w*16 + n
    f16x8 Ah[4], Al[4], Axh, Axl;
    const int jr = w * 16 + n;
#pragma unroll
    for (int kc = 0; kc < 4; ++kc) {
        Ah[kc] = *(const f16x8*)(Wh + jr * HIDN + kc * 32 + q * 8);
        Al[kc] = *(const f16x8*)(Wl + jr * HIDN + kc * 32 + q * 8);
    }
    Axh = *(const f16x8*)(Wch + jr * CIN + q * 8);
    Axl = *(const f16x8*)(Wcl + jr * CIN + q * 8);
    float4 bv = *(const float4*)(bpre + w * 16 + q * 4);
    f32x4 bp = (f32x4){bv.x, bv.y, bv.z, bv.w};
    const f32x4 zero4 = (f32x4){0.f, 0.f, 0.f, 0.f};

    // x B-frag stream: lane (n,q) reads xT[t][bb*16+n][q*8 .. +8]
    const unsigned short* xp = xT + ((size_t)(bb * 16 + n) * CIN + q * 8);
    f16x8 xb0, xb1;
    xb0 = *(const f16x8*)(xp);                       // t = 0 (in flight over prologue)

    // ---- h0 -> fp16 plane, dbuf 0 (first 256 threads) ----
    if (tid < 256) {
        const int ni = tid >> 4, gi = tid & 15;
        const float4* src = (const float4*)(h0 + ((size_t)bb * 16 + ni) * HIDN + gi * 8);
        float4 a = src[0], b4 = src[1];
        float vv[8] = {a.x, a.y, a.z, a.w, b4.x, b4.y, b4.z, b4.w};
        unsigned short o[8];
#pragma unroll
        for (int i = 0; i < 8; ++i) o[i] = f16b((_Float16)vv[i]);
        *(uint4*)&hbuf[0][ni][(gi ^ (ni & 7)) * 8] = *(uint4*)o;
    }
    __syncthreads();

    unsigned short* hsp = hs + ((size_t)bb * 16 + n) * HIDN + w * 16 + q * 4;
    const int G = (w * 2 + (q >> 1)) ^ (n & 7);
    const int sw = n & 7;

#define STEP(T, IN, OUT, XCUR, XNEXT)                                          \
    {                                                                          \
        XNEXT = *(const f16x8*)(xp + (size_t)((T) + 1) * (BATCH * CIN));       \
        f16x8 Bh0 = *(const f16x8*)&hbuf[IN][n][((0 + q) ^ sw) * 8];           \
        f16x8 Bh1 = *(const f16x8*)&hbuf[IN][n][((4 + q) ^ sw) * 8];           \
        f16x8 Bh2 = *(const f16x8*)&hbuf[IN][n][((8 + q) ^ sw) * 8];           \
        f16x8 Bh3 = *(const f16x8*)&hbuf[IN][n][((12 + q) ^ sw) * 8];          \
        f32x4 c0 = MFMA16(Axh, XCUR, bp);                                      \
        f32x4 c2 = MFMA16(Axl, XCUR, zero4);                                   \
        c0 = MFMA16(Ah[0], Bh0, c0);                                           \
        c2 = MFMA16(Al[0], Bh0, c2);                                           \
        f32x4 c1 = MFMA16(Ah[1], Bh1, zero4);                                  \
        f32x4 c3 = MFMA16(Al[1], Bh1, zero4);                                  \
        c0 = MFMA16(Ah[2], Bh2, c0);                                           \
        c2 = MFMA16(Al[2], Bh2, c2);                                           \
        c1 = MFMA16(Ah[3], Bh3, c1);                                           \
        c3 = MFMA16(Al[3], Bh3, c3);                                           \
        f32x4 acc = (c0 + c1) + (c2 + c3);                                     \
        unsigned short o[4];                                                   \
        for (int r = 0; r < 4; ++r) {                                          \
            float e = __expf(2.f * acc[r]);                                    \
            float hv = 1.f - 2.f * __builtin_amdgcn_rcpf(e + 1.f);             \
            o[r] = f16b((_Float16)hv);                                         \
        }                                                                      \
        uint2 pk; __builtin_memcpy(&pk, o, 8);                                 \
        *(uint2*)&hbuf[OUT][n][G * 8 + (q & 1) * 4] = pk;                      \
        *(uint2*)(hsp + (size_t)(T) * (BATCH * HIDN)) = pk;                    \
        asm volatile("" ::: "memory");                                         \
        __builtin_amdgcn_s_waitcnt(0xC07F); /* lgkmcnt(0) only */              \
        __builtin_amdgcn_s_barrier();                                          \
        asm volatile("" ::: "memory");                                         \
    }

    for (int t = 0; t < L; t += 2) {
        STEP(t,     0, 1, xb0, xb1);
        STEP(t + 1, 1, 0, xb1, xb0);
    }
#undef STEP
}

// Fused upsample(16->32, align_corners) + hardswish + mean + out-GEMM.
__global__ __launch_bounds__(256) void pool_out_kernel(
    const unsigned short* __restrict__ hs, const float* __restrict__ W_out,
    const float* __restrict__ b_out, float* __restrict__ out)
{
    const int b = blockIdx.x, tid = threadIdx.x;
    __shared__ unsigned short m[L][HIDN];   // 64 KB fp16
    __shared__ float ps[2][HIDN];
    __shared__ float pooled_s[HIDN];

#pragma unroll
    for (int it = 0; it < 16; ++it) {
        int i = tid + it * 256;             // uint4 granule = 8 fp16
        int t = i >> 4, g = i & 15;
        *(uint4*)&m[t][g * 8] =
            *(const uint4*)(hs + (size_t)t * (BATCH * HIDN) + b * HIDN + g * 8);
    }
    __syncthreads();

    const int jo = tid & 127, sub = tid >> 7;
    float acc = 0.f;
    for (int oy = sub * 16; oy < sub * 16 + 16; ++oy) {
        float ysf = oy * (15.f / 31.f);
        int y0 = (int)ysf; float wy = ysf - (float)y0; int y1 = min(y0 + 1, 15);
        float rb[16];
#pragma unroll
        for (int sx = 0; sx < 16; ++sx) {
            float v0 = (float)*(const _Float16*)&m[y0 * 16 + sx][jo];
            float v1 = (float)*(const _Float16*)&m[y1 * 16 + sx][jo];
            rb[sx] = v0 + wy * (v1 - v0);
        }
#pragma unroll
        for (int ox = 0; ox < 32; ++ox) {
            float xsf = ox * (15.f / 31.f);
            int x0 = (int)xsf; float wx = xsf - (float)x0; int x1 = min(x0 + 1, 15);
            float v = rb[x0] + wx * (rb[x1] - rb[x0]);
            float t6 = fminf(fmaxf(v + 3.f, 0.f), 6.f);
            acc += v * t6;
        }
    }
    ps[sub][jo] = acc;
    __syncthreads();
    if (tid < 128) pooled_s[tid] = (ps[0][tid] + ps[1][tid]) * (1.f / 6144.f);
    __syncthreads();

    for (int o = tid; o < OUTN; o += 256) {
        float a = b_out[o];
#pragma unroll 8
        for (int k = 0; k < HIDN; k += 4) {
            float4 wv = *(const float4*)(W_out + o * HIDN + k);
            float4 pv = *(const float4*)&pooled_s[k];
            a += wv.x * pv.x + wv.y * pv.y + wv.z * pv.z + wv.w * pv.w;
        }
        out[b * OUTN + o] = a;
    }
}

extern "C" void kernel_launch(void* const* d_in, const int* in_sizes, int n_in,
                              void* d_out, int out_size, void* d_ws, size_t ws_size,
                              hipStream_t stream)
{
    const float* x     = (const float*)d_in[0];
    const float* h0    = (const float*)d_in[1];
    const float* W_in  = (const float*)d_in[2];
    const float* b_in  = (const float*)d_in[3];
    const float* W_ih  = (const float*)d_in[4];
    const float* b_ih  = (const float*)d_in[5];
    const float* W_hh  = (const float*)d_in[6];
    const float* b_hh  = (const float*)d_in[7];
    const float* W_out = (const float*)d_in[8];
    const float* b_out = (const float*)d_in[9];
    float* out = (float*)d_out;

    char* wsb = (char*)d_ws;
    unsigned short* Wh  = (unsigned short*)(wsb);
    unsigned short* Wl  = (unsigned short*)(wsb + 32768);
    unsigned short* Wch = (unsigned short*)(wsb + 65536);
    unsigned short* Wcl = (unsigned short*)(wsb + 73728);
    float* bpre         = (float*)(wsb + 81920);
    unsigned short* hsb = (unsigned short*)(wsb + 98304);
    unsigned short* xT  = (unsigned short*)(wsb + 33652736);  // 257*512*32 fp16

    prep_kernel<<<33, 256, 0, stream>>>(x, W_in, b_in, W_ih, b_ih, b_hh, W_hh,
                                        Wh, Wl, Wch, Wcl, bpre, xT);
    rnn_kernel<<<32, 512, 0, stream>>>(h0, Wh, Wl, Wch, Wcl, bpre, xT, hsb);
    pool_out_kernel<<<512, 256, 0, stream>>>(hsb, W_out, b_out, out);
}

// Round 2
// 217.056 us; speedup vs baseline: 1.1291x; 1.1291x over previous
//
#include <hip/hip_runtime.h>

#define L 256
#define BATCH 512
#define CIN 32
#define HIDN 128
#define OUTN 512

typedef _Float16 f16x8 __attribute__((ext_vector_type(8)));
typedef float f32x4 __attribute__((ext_vector_type(4)));

#define MFMA16(a, b, c) __builtin_amdgcn_mfma_f32_16x16x32_f16(a, b, c, 0, 0, 0)

static __device__ __forceinline__ unsigned short f16b(_Float16 h) {
    unsigned short u; __builtin_memcpy(&u, &h, 2); return u;
}

// ws layout (bytes):
//   Wh   @ 0      (32768)  fp16 hi of W_hh [j][k]
//   Wl   @ 32768  (32768)  fp16 lo residual (W to 22 bits; systematic error)
//   Wch  @ 65536  (8192)   fp16 hi of Wc = W_ih@W_in [j][c]
//   Wcl  @ 73728  (8192)
//   bpre @ 81920  (512)    fp32 b_ih + b_hh + W_ih@b_in
//   hs   @ 98304  (33554432) fp16 hs[t*65536 + b*128 + j]

__global__ __launch_bounds__(256) void prep_kernel(
    const float* __restrict__ W_in, const float* __restrict__ b_in,
    const float* __restrict__ W_ih, const float* __restrict__ b_ih,
    const float* __restrict__ b_hh, const float* __restrict__ Whh,
    unsigned short* __restrict__ Wh, unsigned short* __restrict__ Wl,
    unsigned short* __restrict__ Wch, unsigned short* __restrict__ Wcl,
    float* __restrict__ bpre)
{
    const int tid = threadIdx.x;
    __shared__ float win[64 * CIN];
    for (int i = tid; i < 64 * CIN; i += 256) win[i] = W_in[i];
    __syncthreads();
    if (tid < 128) {
        const int j = tid;
        float acc[CIN];
#pragma unroll
        for (int c = 0; c < CIN; ++c) acc[c] = 0.f;
        float bs = b_ih[j] + b_hh[j];
        for (int m = 0; m < 64; ++m) {
            float w = W_ih[j * 64 + m];
            bs += w * b_in[m];
#pragma unroll
            for (int c = 0; c < CIN; ++c) acc[c] += w * win[m * CIN + c];
        }
        bpre[j] = bs;
#pragma unroll
        for (int c = 0; c < CIN; ++c) {
            _Float16 h = (_Float16)acc[c];
            _Float16 l = (_Float16)(acc[c] - (float)h);
            Wch[j * CIN + c] = f16b(h);
            Wcl[j * CIN + c] = f16b(l);
        }
    } else {
        const int j = tid - 128;
        for (int k = 0; k < HIDN; k += 4) {
            float4 v = *(const float4*)(Whh + j * HIDN + k);
            float vv[4] = {v.x, v.y, v.z, v.w};
#pragma unroll
            for (int u = 0; u < 4; ++u) {
                _Float16 h = (_Float16)vv[u];
                _Float16 l = (_Float16)(vv[u] - (float)h);
                Wh[j * HIDN + k + u] = f16b(h);
                Wl[j * HIDN + k + u] = f16b(l);
            }
        }
    }
}

// MFMA RNN, fp16 2-term split. 32 blocks (16 batch rows) x 512 thr (8 waves).
// R11 (revert of R10's global-xT regression, keep its chain split):
//  - xc LDS staging back (R9 structure), but with a lane-linear granule layout
//    [tt][gr= q*16 + (n^4q)][8c]: each wave's per-step xB read is one
//    contiguous 1 KB row -> provably conflict-free. Staging writes (scalar
//    u16, every 16 steps) keep minor conflicts: <10 cyc/step amortized.
//  - write_chunk moved tt==15 -> tt==14 so the NEXT step's xB can be
//    register-prefetched at the end of every step without racing staging.
//  - barrier guard is lgkmcnt(1), not (0): in-order lgkm retirement drains
//    all ds_writes (older) while the xB prefetch read (youngest) stays in
//    flight across the barrier. Next step's 2 x-MFMAs then issue immediately
//    post-barrier (operands all in regs), overlapping the ~120-cyc ds_read
//    latency of the 4 hbuf fragments.
//  - 4-accumulator MFMA split (3+3+2+2) kept from R10 (absmax identical).
__global__ __launch_bounds__(512, 1) void rnn_kernel(
    const float* __restrict__ x, const float* __restrict__ h0,
    const unsigned short* __restrict__ Wh, const unsigned short* __restrict__ Wl,
    const unsigned short* __restrict__ Wch, const unsigned short* __restrict__ Wcl,
    const float* __restrict__ bpre, unsigned short* __restrict__ hs)
{
    const int tid = threadIdx.x;
    const int bb = blockIdx.x;
    const int lane = tid & 63;
    const int w = tid >> 6;       // wave 0..7
    const int n = lane & 15;      // batch col / B col
    const int q = lane >> 4;      // quad

    __shared__ unsigned short hbuf[2][16][HIDN];     // 8 KB, granule swizzle ^(n&7)
    __shared__ unsigned short xcl[2][16][64][8];     // 32 KB, [buf][tt][granule][c&7]

    // A-frags: rows = j = w*16 + n
    f16x8 Ah[4], Al[4], Axh, Axl;
    const int jr = w * 16 + n;
#pragma unroll
    for (int kc = 0; kc < 4; ++kc) {
        Ah[kc] = *(const f16x8*)(Wh + jr * HIDN + kc * 32 + q * 8);
        Al[kc] = *(const f16x8*)(Wl + jr * HIDN + kc * 32 + q * 8);
    }
    Axh = *(const f16x8*)(Wch + jr * CIN + q * 8);
    Axl = *(const f16x8*)(Wcl + jr * CIN + q * 8);
    float4 bv = *(const float4*)(bpre + w * 16 + q * 4);
    f32x4 bp = (f32x4){bv.x, bv.y, bv.z, bv.w};
    const f32x4 zero4 = (f32x4){0.f, 0.f, 0.f, 0.f};

    // ---- h0 -> fp16 plane, dbuf 0 (first 256 threads) ----
    if (tid < 256) {
        const int ni = tid >> 4, gi = tid & 15;
        const float4* src = (const float4*)(h0 + ((size_t)bb * 16 + ni) * HIDN + gi * 8);
        float4 a = src[0], b4 = src[1];
        float vv[8] = {a.x, a.y, a.z, a.w, b4.x, b4.y, b4.z, b4.w};
        unsigned short o[8];
#pragma unroll
        for (int i = 0; i < 8; ++i) o[i] = f16b((_Float16)vv[i]);
        *(uint4*)&hbuf[0][ni][(gi ^ (ni & 7)) * 8] = *(uint4*)o;
    }

    // ---- x chunk staging over 512 threads: i=tid+r*512 -> (nn,cc,tq) ----
    float4 xr[4];
    auto issue_chunk = [&](int ci) {
#pragma unroll
        for (int r = 0; r < 4; ++r) {
            int i = tid + r * 512;
            int nn = i >> 7, cc = (i >> 2) & 31, tq = i & 3;
            xr[r] = *(const float4*)(x + (((size_t)bb * 16 + nn) * CIN + cc) * L + ci * 16 + tq * 4);
        }
    };
    auto write_chunk = [&](int buf) {
#pragma unroll
        for (int r = 0; r < 4; ++r) {
            int i = tid + r * 512;
            int nn = i >> 7, cc = (i >> 2) & 31, tq = i & 3;
            int gr = (cc >> 3) * 16 + (nn ^ ((cc >> 3) << 2));
            float vv[4] = {xr[r].x, xr[r].y, xr[r].z, xr[r].w};
#pragma unroll
            for (int k = 0; k < 4; ++k)
                xcl[buf][tq * 4 + k][gr][cc & 7] = f16b((_Float16)vv[k]);
        }
    };

    issue_chunk(0);
    write_chunk(0);
    issue_chunk(1);
    __syncthreads();

    unsigned short* hsp = hs + ((size_t)bb * 16 + n) * HIDN + w * 16 + q * 4;
    const int G = (w * 2 + (q >> 1)) ^ (n & 7);
    const int sw = n & 7;
    const int grs = q * 16 + (n ^ (q << 2));   // this lane's xc granule

    f16x8 xb0, xb1;
    xb0 = *(const f16x8*)&xcl[0][0][grs][0];   // t=0 fragment

#define STEP(T, IN, OUT, OFF, XCUR, XNEXT)                                     \
    {                                                                          \
        f16x8 Bh0 = *(const f16x8*)&hbuf[IN][n][((0 + q) ^ sw) * 8];           \
        f16x8 Bh1 = *(const f16x8*)&hbuf[IN][n][((4 + q) ^ sw) * 8];           \
        f16x8 Bh2 = *(const f16x8*)&hbuf[IN][n][((8 + q) ^ sw) * 8];           \
        f16x8 Bh3 = *(const f16x8*)&hbuf[IN][n][((12 + q) ^ sw) * 8];          \
        f32x4 c0 = MFMA16(Axh, XCUR, bp);      /* operands all in regs */      \
        f32x4 c2 = MFMA16(Axl, XCUR, zero4);                                   \
        c0 = MFMA16(Ah[0], Bh0, c0);                                           \
        c2 = MFMA16(Al[0], Bh0, c2);                                           \
        f32x4 c1 = MFMA16(Ah[1], Bh1, zero4);                                  \
        f32x4 c3 = MFMA16(Al[1], Bh1, zero4);                                  \
        c0 = MFMA16(Ah[2], Bh2, c0);                                           \
        c2 = MFMA16(Al[2], Bh2, c2);                                           \
        c1 = MFMA16(Ah[3], Bh3, c1);                                           \
        c3 = MFMA16(Al[3], Bh3, c3);                                           \
        if (((T) & 15) == 14 && (T) < L - 16) {                                \
            write_chunk((((T) >> 4) & 1) ^ 1);                                 \
            if ((T) < L - 32) issue_chunk(((T) >> 4) + 2);                     \
        }                                                                      \
        f32x4 acc = (c0 + c1) + (c2 + c3);                                     \
        unsigned short o[4];                                                   \
        for (int r = 0; r < 4; ++r) {                                          \
            float e = __expf(2.f * acc[r]);                                    \
            float hv = 1.f - 2.f * __builtin_amdgcn_rcpf(e + 1.f);             \
            o[r] = f16b((_Float16)hv);                                         \
        }                                                                      \
        uint2 pk; __builtin_memcpy(&pk, o, 8);                                 \
        *(uint2*)&hbuf[OUT][n][G * 8 + (q & 1) * 4] = pk;                      \
        *(uint2*)(hsp + (OFF)) = pk;                                           \
        XNEXT = *(const f16x8*)&xcl[(((T) + 1) >> 4) & 1][((T) + 1) & 15][grs][0]; \
        asm volatile("" ::: "memory");                                         \
        __builtin_amdgcn_s_waitcnt(0xC17F);  /* lgkmcnt(1): writes drained, */ \
        __builtin_amdgcn_s_barrier();        /* xB prefetch stays in flight */ \
        asm volatile("" ::: "memory");                                         \
    }

    for (int t = 0; t < L; t += 2) {
        STEP(t,     0, 1, 0,             xb0, xb1);
        STEP(t + 1, 1, 0, BATCH * HIDN,  xb1, xb0);
        hsp += 2 * (BATCH * HIDN);
    }
#undef STEP
}

// Fused upsample(16->32, align_corners) + hardswish + mean + out-GEMM.
__global__ __launch_bounds__(256) void pool_out_kernel(
    const unsigned short* __restrict__ hs, const float* __restrict__ W_out,
    const float* __restrict__ b_out, float* __restrict__ out)
{
    const int b = blockIdx.x, tid = threadIdx.x;
    __shared__ unsigned short m[L][HIDN];   // 64 KB fp16
    __shared__ float ps[2][HIDN];
    __shared__ float pooled_s[HIDN];

#pragma unroll
    for (int it = 0; it < 16; ++it) {
        int i = tid + it * 256;             // uint4 granule = 8 fp16
        int t = i >> 4, g = i & 15;
        *(uint4*)&m[t][g * 8] =
            *(const uint4*)(hs + (size_t)t * (BATCH * HIDN) + b * HIDN + g * 8);
    }
    __syncthreads();

    const int jo = tid & 127, sub = tid >> 7;
    float acc = 0.f;
    for (int oy = sub * 16; oy < sub * 16 + 16; ++oy) {
        float ysf = oy * (15.f / 31.f);
        int y0 = (int)ysf; float wy = ysf - (float)y0; int y1 = min(y0 + 1, 15);
        float rb[16];
#pragma unroll
        for (int sx = 0; sx < 16; ++sx) {
            float v0 = (float)*(const _Float16*)&m[y0 * 16 + sx][jo];
            float v1 = (float)*(const _Float16*)&m[y1 * 16 + sx][jo];
            rb[sx] = v0 + wy * (v1 - v0);
        }
#pragma unroll
        for (int ox = 0; ox < 32; ++ox) {
            float xsf = ox * (15.f / 31.f);
            int x0 = (int)xsf; float wx = xsf - (float)x0; int x1 = min(x0 + 1, 15);
            float v = rb[x0] + wx * (rb[x1] - rb[x0]);
            float t6 = fminf(fmaxf(v + 3.f, 0.f), 6.f);
            acc += v * t6;
        }
    }
    ps[sub][jo] = acc;
    __syncthreads();
    if (tid < 128) pooled_s[tid] = (ps[0][tid] + ps[1][tid]) * (1.f / 6144.f);
    __syncthreads();

    for (int o = tid; o < OUTN; o += 256) {
        float a = b_out[o];
#pragma unroll 8
        for (int k = 0; k < HIDN; k += 4) {
            float4 wv = *(const float4*)(W_out + o * HIDN + k);
            float4 pv = *(const float4*)&pooled_s[k];   // broadcast b128
            a += wv.x * pv.x + wv.y * pv.y + wv.z * pv.z + wv.w * pv.w;
        }
        out[b * OUTN + o] = a;
    }
}

extern "C" void kernel_launch(void* const* d_in, const int* in_sizes, int n_in,
                              void* d_out, int out_size, void* d_ws, size_t ws_size,
                              hipStream_t stream)
{
    const float* x     = (const float*)d_in[0];
    const float* h0    = (const float*)d_in[1];
    const float* W_in  = (const float*)d_in[2];
    const float* b_in  = (const float*)d_in[3];
    const float* W_ih  = (const float*)d_in[4];
    const float* b_ih  = (const float*)d_in[5];
    const float* W_hh  = (const float*)d_in[6];
    const float* b_hh  = (const float*)d_in[7];
    const float* W_out = (const float*)d_in[8];
    const float* b_out = (const float*)d_in[9];
    float* out = (float*)d_out;

    char* wsb = (char*)d_ws;
    unsigned short* Wh  = (unsigned short*)(wsb);
    unsigned short* Wl  = (unsigned short*)(wsb + 32768);
    unsigned short* Wch = (unsigned short*)(wsb + 65536);
    unsigned short* Wcl = (unsigned short*)(wsb + 73728);
    float* bpre         = (float*)(wsb + 81920);
    unsigned short* hsb = (unsigned short*)(wsb + 98304);

    prep_kernel<<<1, 256, 0, stream>>>(W_in, b_in, W_ih, b_ih, b_hh, W_hh,
                                       Wh, Wl, Wch, Wcl, bpre);
    rnn_kernel<<<32, 512, 0, stream>>>(x, h0, Wh, Wl, Wch, Wcl, bpre, hsb);
    pool_out_kernel<<<512, 256, 0, stream>>>(hsb, W_out, b_out, out);
}